// Round 11
// baseline (258.051 us; speedup 1.0000x reference)
//
#include <hip/hip_runtime.h>
#include <math.h>

static constexpr int N_NODES = 100000;
static constexpr int N_EDGES = 3200000;
static constexpr int F_INC   = 256;
static constexpr int HIDC    = 16;
static constexpr int NCLS    = 32;

static constexpr int BNODES  = 256;                              // nodes per bucket
static constexpr int NBKT    = (N_NODES + BNODES - 1) / BNODES;  // 391
static constexpr int CAP     = 9216;                             // slab slots per bucket
static constexpr int CHUNK   = 4096;                             // edges per bucketing block
static constexpr int NCHUNK  = (N_EDGES + CHUNK - 1) / CHUNK;    // 782

// ---- bf16 pair helpers (RNE round) ----
__device__ __forceinline__ unsigned pack_bf2(float a, float b) {
    unsigned ua = __float_as_uint(a);
    unsigned ub = __float_as_uint(b);
    ua = (ua + 0x7FFFu + ((ua >> 16) & 1u)) >> 16;
    ub = (ub + 0x7FFFu + ((ub >> 16) & 1u)) & 0xFFFF0000u;
    return ua | ub;
}
__device__ __forceinline__ float bflo(unsigned v) { return __uint_as_float(v << 16); }
__device__ __forceinline__ float bfhi(unsigned v) { return __uint_as_float(v & 0xFFFF0000u); }
__device__ __forceinline__ float elu1(float t) { return t > 0.f ? t : expm1f(t); }

__global__ void k_zero_cur(int* gcur) {
    int i = threadIdx.x;
    if (i < NBKT) gcur[i] = 0;
}

// Bin a chunk of 4096 edges by dst bucket in LDS, flush bucket-sorted runs to the slab.
__global__ __launch_bounds__(256) void k_bucket(const int* __restrict__ src,
                                                const int* __restrict__ dst,
                                                int* gcur, unsigned int* __restrict__ slab) {
    __shared__ int hist[512];
    __shared__ int sc[512];
    __shared__ int place[512];
    __shared__ int gbase[512];
    __shared__ unsigned int staging[CHUNK];
    __shared__ unsigned short bid[CHUNK];
    int tid = threadIdx.x;
    int e0 = blockIdx.x * CHUNK;
    int n = min(CHUNK, N_EDGES - e0);
    hist[tid] = 0; hist[tid + 256] = 0;
    __syncthreads();
    unsigned int pay[16];
    int bk[16];
    #pragma unroll
    for (int r = 0; r < 16; ++r) {
        int i = r * 256 + tid;
        bk[r] = -1;
        if (i < n) {
            int e = e0 + i;
            int s = src[e];
            int t = dst[e];
            int b = t >> 8;
            pay[r] = (unsigned)s | ((unsigned)(t & 255) << 24);
            bk[r] = b;
            atomicAdd(&hist[b], 1);
        }
    }
    __syncthreads();
    sc[tid] = hist[tid]; sc[tid + 256] = hist[tid + 256];
    __syncthreads();
    for (int off = 1; off < 512; off <<= 1) {
        int i0 = tid, i1 = tid + 256;
        int v0 = (i0 >= off) ? sc[i0 - off] : 0;
        int v1 = (i1 >= off) ? sc[i1 - off] : 0;
        __syncthreads();
        sc[i0] += v0; sc[i1] += v1;
        __syncthreads();
    }
    {
        int b0 = tid, b1 = tid + 256;
        int o0 = sc[b0] - hist[b0];
        int o1 = sc[b1] - hist[b1];
        place[b0] = o0; place[b1] = o1;
        sc[b0] = o0; sc[b1] = o1;
        if (b0 < NBKT && hist[b0]) gbase[b0] = atomicAdd(&gcur[b0], hist[b0]);
        if (b1 < NBKT && hist[b1]) gbase[b1] = atomicAdd(&gcur[b1], hist[b1]);
    }
    __syncthreads();
    #pragma unroll
    for (int r = 0; r < 16; ++r) {
        if (bk[r] >= 0) {
            int p = atomicAdd(&place[bk[r]], 1);
            staging[p] = pay[r];
            bid[p] = (unsigned short)bk[r];
        }
    }
    __syncthreads();
    for (int i = tid; i < n; i += 256) {
        int b = bid[i];
        int gp = gbase[b] + (i - sc[b]);
        if (gp < CAP) slab[(size_t)b * CAP + gp] = staging[i];
    }
}

// Per bucket: histogram local dst, scan, reorder in LDS, write back in place
// (coalesced, sorted by dst). Emits rowptr/cnt/dis.
__global__ __launch_bounds__(512) void k_csr(const int* __restrict__ gcur,
                                             unsigned int* __restrict__ slab,
                                             int* __restrict__ rowptr,
                                             int* __restrict__ cnt,
                                             float* __restrict__ dis) {
    __shared__ int hist[BNODES];
    __shared__ int lofs[BNODES];
    __shared__ int place[BNODES];
    __shared__ unsigned int reord[CAP];
    int tid = threadIdx.x, b = blockIdx.x;
    if (tid < BNODES) hist[tid] = 0;
    __syncthreads();
    int count = min(gcur[b], CAP);
    unsigned int* sl = slab + (size_t)b * CAP;
    for (int i = tid; i < count; i += 512) atomicAdd(&hist[sl[i] >> 24], 1);
    __syncthreads();
    if (tid < BNODES) lofs[tid] = hist[tid];
    __syncthreads();
    for (int off = 1; off < BNODES; off <<= 1) {
        int v = 0;
        if (tid < BNODES && tid >= off) v = lofs[tid - off];
        __syncthreads();
        if (tid < BNODES) lofs[tid] += v;
        __syncthreads();
    }
    if (tid < BNODES) {
        int ex = lofs[tid] - hist[tid];
        lofs[tid] = ex;
        place[tid] = ex;
        int node = b * BNODES + tid;
        if (node < N_NODES) {
            rowptr[node] = b * CAP + ex;
            cnt[node] = hist[tid];
            dis[node] = rsqrtf((float)hist[tid] + 1.0f);
        }
    }
    __syncthreads();
    for (int i = tid; i < count; i += 512) {
        unsigned int v = sl[i];
        int dl = v >> 24;
        int p = atomicAdd(&place[dl], 1);
        reord[p] = v & 0xFFFFFFu;
    }
    __syncthreads();
    for (int i = tid; i < count; i += 512) sl[i] = reord[i];
}

// h1 = x @ W1, pre-scaled by dis[n], packed bf16.
// One WAVE per row (grid-stride). Lane = (g = lane>>4, j = lane&15).
// x: per k4-iter the wave loads ONE float4 per g-group (4 distinct lines,
// HW-merged broadcast across the 16 j-lanes) -> ~4 transactions/instr.
// W: 8KB LDS table of bf16-pairs laid out [2i+c2][lane] -> consecutive lanes
// hit consecutive banks (2 lanes/bank = free), zero conflicts, 2 ds_read_b32
// per iter. Reduce over g via 2 shfl_xor; 8 lanes store packed bf16 pairs.
__global__ __launch_bounds__(256) void k_linear1(const float* __restrict__ x,
                                                 const float* __restrict__ W1,
                                                 const float* __restrict__ dis,
                                                 unsigned* __restrict__ hb) {
    __shared__ unsigned Wb[2048];   // 8 KB
    int tid = threadIdx.x;
    for (int idx = tid; idx < 2048; idx += 256) {
        int i  = idx >> 7;          // k4 index 0..15
        int c2 = (idx >> 6) & 1;
        int ln = idx & 63;
        int g = ln >> 4, j = ln & 15;
        int k0 = g * 64 + 4 * i + 2 * c2;
        Wb[idx] = pack_bf2(W1[k0 * HIDC + j], W1[(k0 + 1) * HIDC + j]);
    }
    __syncthreads();
    int lane = tid & 63;
    int g = lane >> 4;
    int wave = (blockIdx.x * blockDim.x + tid) >> 6;
    int nwaves = (gridDim.x * blockDim.x) >> 6;
    for (int r = wave; r < N_NODES; r += nwaves) {
        const float4* xr = (const float4*)(x + (size_t)r * F_INC + g * 64);
        float acc = 0.f;
        #pragma unroll
        for (int i = 0; i < 16; ++i) {
            float4 v = xr[i];
            unsigned w01 = Wb[(2 * i) * 64 + lane];
            unsigned w23 = Wb[(2 * i + 1) * 64 + lane];
            acc += v.x * bflo(w01) + v.y * bfhi(w01)
                 + v.z * bflo(w23) + v.w * bfhi(w23);
        }
        acc += __shfl_xor(acc, 16);
        acc += __shfl_xor(acc, 32);
        float prt = __shfl_xor(acc, 1);
        float dn = dis[r];   // r wave-uniform -> scalar load
        if (lane < 16 && (lane & 1) == 0)
            hb[(size_t)r * 8 + (lane >> 1)] = pack_bf2(dn * acc, dn * prt);
    }
}

// Pair-lane gather over pre-scaled bf16 table hb (hb[s] = dis[s]*h[s]):
//   agg[n] = dis[n] * ( hb[n] + sum_{s in in(n)} hb[s] )
// POST=0: store agg as f32 (float2 per lane). POST=1: z = elu(agg + bias),
// store pack_bf2(dis[n]*z) (next layer's pre-scaled table).
template<int POST>
__global__ __launch_bounds__(256) void k_gather8(const int* __restrict__ rowptr,
                                                 const int* __restrict__ cnt,
                                                 const unsigned* __restrict__ csr,
                                                 const float* __restrict__ dis,
                                                 const unsigned* __restrict__ hb,
                                                 void* __restrict__ outp,
                                                 const float* __restrict__ bias) {
    int idx = blockIdx.x * blockDim.x + threadIdx.x;
    int n = idx >> 3;
    if (n >= N_NODES) return;
    int q = idx & 7;
    int base = rowptr[n];
    int deg = cnt[n];
    unsigned sv = hb[(size_t)n * 8 + q];
    float acc0 = bflo(sv), acc1 = bfhi(sv);
    int j = 0;
    for (; j + 3 < deg; j += 4) {
        int s0 = csr[base + j];
        int s1 = csr[base + j + 1];
        int s2 = csr[base + j + 2];
        int s3 = csr[base + j + 3];
        unsigned v0 = hb[(size_t)s0 * 8 + q];
        unsigned v1 = hb[(size_t)s1 * 8 + q];
        unsigned v2 = hb[(size_t)s2 * 8 + q];
        unsigned v3 = hb[(size_t)s3 * 8 + q];
        acc0 += (bflo(v0) + bflo(v1)) + (bflo(v2) + bflo(v3));
        acc1 += (bfhi(v0) + bfhi(v1)) + (bfhi(v2) + bfhi(v3));
    }
    for (; j < deg; ++j) {
        int s = csr[base + j];
        unsigned v = hb[(size_t)s * 8 + q];
        acc0 += bflo(v);
        acc1 += bfhi(v);
    }
    float dn = dis[n];
    acc0 *= dn; acc1 *= dn;
    if (POST == 0) {
        ((float2*)outp)[(size_t)n * 8 + q] = make_float2(acc0, acc1);
    } else {
        float z0 = elu1(acc0 + bias[2 * q]);
        float z1 = elu1(acc1 + bias[2 * q + 1]);
        ((unsigned*)outp)[(size_t)n * 8 + q] = pack_bf2(dn * z0, dn * z1);
    }
}

// h2 = elu(agg1 + b1) @ W2, stored pre-scaled by dis[n] as packed bf16.
__global__ __launch_bounds__(256) void k_finlin16(const float* __restrict__ agg,
                                                  const float* __restrict__ bias,
                                                  const float* __restrict__ W,
                                                  const float* __restrict__ dis,
                                                  unsigned* __restrict__ hb) {
    __shared__ float Ws[HIDC * HIDC];
    __shared__ float bs[HIDC];
    for (int i = threadIdx.x; i < HIDC * HIDC; i += 256) Ws[i] = W[i];
    if (threadIdx.x < HIDC) bs[threadIdx.x] = bias[threadIdx.x];
    __syncthreads();
    int n = blockIdx.x * blockDim.x + threadIdx.x;
    if (n >= N_NODES) return;
    float act[HIDC];
    const float4* ar = (const float4*)(agg + (size_t)n * HIDC);
    #pragma unroll
    for (int k4 = 0; k4 < 4; ++k4) {
        float4 v = ar[k4];
        act[4 * k4 + 0] = elu1(v.x + bs[4 * k4 + 0]);
        act[4 * k4 + 1] = elu1(v.y + bs[4 * k4 + 1]);
        act[4 * k4 + 2] = elu1(v.z + bs[4 * k4 + 2]);
        act[4 * k4 + 3] = elu1(v.w + bs[4 * k4 + 3]);
    }
    float acc[HIDC];
    #pragma unroll
    for (int j = 0; j < HIDC; ++j) acc[j] = 0.f;
    #pragma unroll
    for (int k = 0; k < HIDC; ++k) {
        float a = act[k];
        #pragma unroll
        for (int j = 0; j < HIDC; ++j) acc[j] += a * Ws[k * HIDC + j];
    }
    float dn = dis[n];
    unsigned o[8];
    #pragma unroll
    for (int q = 0; q < 8; ++q) o[q] = pack_bf2(dn * acc[2 * q], dn * acc[2 * q + 1]);
    uint4* ob = (uint4*)(hb + (size_t)n * 8);
    ob[0] = make_uint4(o[0], o[1], o[2], o[3]);
    ob[1] = make_uint4(o[4], o[5], o[6], o[7]);
}

// out = log_softmax(elu(g @ W3 + b3)); one class per lane, 32 lanes per node.
__global__ __launch_bounds__(256) void k_final32(const float* __restrict__ g,
                                                 const float* __restrict__ W3,
                                                 const float* __restrict__ b3,
                                                 float* __restrict__ out) {
    __shared__ float Ws[HIDC * NCLS];
    __shared__ float bs[NCLS];
    for (int i = threadIdx.x; i < HIDC * NCLS; i += 256) Ws[i] = W3[i];
    if (threadIdx.x < NCLS) bs[threadIdx.x] = b3[threadIdx.x];
    __syncthreads();
    int idx = blockIdx.x * blockDim.x + threadIdx.x;
    int n = idx >> 5;
    int j = idx & 31;
    if (n >= N_NODES) return;
    float gval = (j < HIDC) ? g[(size_t)n * HIDC + j] : 0.f;
    float r = bs[j];
    #pragma unroll
    for (int k = 0; k < HIDC; ++k)
        r += __shfl(gval, k, 32) * Ws[k * NCLS + j];
    r = elu1(r);
    float m = r;
    #pragma unroll
    for (int off = 16; off > 0; off >>= 1) m = fmaxf(m, __shfl_xor(m, off, 32));
    float s = expf(r - m);
    #pragma unroll
    for (int off = 16; off > 0; off >>= 1) s += __shfl_xor(s, off, 32);
    out[idx] = r - (logf(s) + m);
}

extern "C" void kernel_launch(void* const* d_in, const int* in_sizes, int n_in,
                              void* d_out, int out_size, void* d_ws, size_t ws_size,
                              hipStream_t stream) {
    const float* x  = (const float*)d_in[0];
    const int*   ei = (const int*)d_in[1];
    const float* W1 = (const float*)d_in[2];
    const float* b1 = (const float*)d_in[3];
    const float* W2 = (const float*)d_in[4];
    const float* b2 = (const float*)d_in[5];
    const float* W3 = (const float*)d_in[6];
    const float* b3 = (const float*)d_in[7];
    float* out = (float*)d_out;
    const int* src = ei;
    const int* dst = ei + N_EDGES;

    // workspace layout (4-byte elements)
    int* wi = (int*)d_ws;
    int*          gcur   = wi;                                   // 512
    unsigned int* slab   = (unsigned int*)(wi + 512);            // NBKT*CAP = 3,603,456
    int*          rowptr = wi + 512 + NBKT * CAP;                // 102,400
    int*          cnt    = rowptr + 102400;                      // 102,400
    float*        dis    = (float*)(cnt + 102400);               // 102,400
    unsigned*     Bh     = (unsigned*)(dis + 102400);            // 819,200 (N*8 bf16-pairs)
    unsigned*     Zb     = Bh + 819200;                          // 819,200
    float*        C      = (float*)(Zb + 819200);                // 1,638,400 (N*16 f32)
    (void)ws_size; (void)n_in; (void)in_sizes; (void)out_size;

    auto blocks = [](long long n) { return (int)((n + 255) / 256); };
    const int GNODE = blocks(N_NODES);                  // 391
    const int GGATH = blocks((long long)N_NODES * 8);   // 3125
    const int GFIN  = blocks((long long)N_NODES * 32);  // 12500

    k_zero_cur<<<1, 512, 0, stream>>>(gcur);
    k_bucket<<<NCHUNK, 256, 0, stream>>>(src, dst, gcur, slab);
    k_csr<<<NBKT, 512, 0, stream>>>(gcur, slab, rowptr, cnt, dis);

    // Layer 1: h1 = x@W1 (pre-scaled bf16) -> a1 = N(h1)
    k_linear1<<<2048, 256, 0, stream>>>(x, W1, dis, Bh);
    k_gather8<0><<<GGATH, 256, 0, stream>>>(rowptr, cnt, slab, dis, Bh, C, nullptr);
    // h2 = elu(a1+b1)@W2 (pre-scaled bf16)
    k_finlin16<<<GNODE, 256, 0, stream>>>(C, b1, W2, dis, Bh);
    // Layer 2: a2 = N(h2); z2 = elu(a2+b2) stored pre-scaled bf16
    k_gather8<1><<<GGATH, 256, 0, stream>>>(rowptr, cnt, slab, dis, Bh, Zb, b2);
    // Layer 3: g = N(z2) [f32]; out = log_softmax(elu(g@W3 + b3))
    k_gather8<0><<<GGATH, 256, 0, stream>>>(rowptr, cnt, slab, dis, Zb, C, nullptr);
    k_final32<<<GFIN, 256, 0, stream>>>(C, W3, b3, out);
}

// Round 12
// 184.655 us; speedup vs baseline: 1.3975x; 1.3975x over previous
//
#include <hip/hip_runtime.h>
#include <math.h>

static constexpr int N_NODES = 100000;
static constexpr int N_EDGES = 3200000;
static constexpr int F_INC   = 256;
static constexpr int HIDC    = 16;
static constexpr int NCLS    = 32;

static constexpr int BNODES  = 256;                              // nodes per bucket
static constexpr int NBKT    = (N_NODES + BNODES - 1) / BNODES;  // 391
static constexpr int CAP     = 9216;                             // slab slots per bucket
static constexpr int CHUNK   = 4096;                             // edges per bucketing block
static constexpr int NCHUNK  = (N_EDGES + CHUNK - 1) / CHUNK;    // 782

// ---- bf16 pair helpers (RNE round) ----
__device__ __forceinline__ unsigned pack_bf2(float a, float b) {
    unsigned ua = __float_as_uint(a);
    unsigned ub = __float_as_uint(b);
    ua = (ua + 0x7FFFu + ((ua >> 16) & 1u)) >> 16;
    ub = (ub + 0x7FFFu + ((ub >> 16) & 1u)) & 0xFFFF0000u;
    return ua | ub;
}
__device__ __forceinline__ float bflo(unsigned v) { return __uint_as_float(v << 16); }
__device__ __forceinline__ float bfhi(unsigned v) { return __uint_as_float(v & 0xFFFF0000u); }
__device__ __forceinline__ float elu1(float t) { return t > 0.f ? t : expm1f(t); }

__global__ void k_zero_cur(int* gcur) {
    int i = threadIdx.x;
    if (i < NBKT) gcur[i] = 0;
}

// Bin a chunk of 4096 edges by dst bucket in LDS, flush bucket-sorted runs to the slab.
__global__ __launch_bounds__(256) void k_bucket(const int* __restrict__ src,
                                                const int* __restrict__ dst,
                                                int* gcur, unsigned int* __restrict__ slab) {
    __shared__ int hist[512];
    __shared__ int sc[512];
    __shared__ int place[512];
    __shared__ int gbase[512];
    __shared__ unsigned int staging[CHUNK];
    __shared__ unsigned short bid[CHUNK];
    int tid = threadIdx.x;
    int e0 = blockIdx.x * CHUNK;
    int n = min(CHUNK, N_EDGES - e0);
    hist[tid] = 0; hist[tid + 256] = 0;
    __syncthreads();
    unsigned int pay[16];
    int bk[16];
    #pragma unroll
    for (int r = 0; r < 16; ++r) {
        int i = r * 256 + tid;
        bk[r] = -1;
        if (i < n) {
            int e = e0 + i;
            int s = src[e];
            int t = dst[e];
            int b = t >> 8;
            pay[r] = (unsigned)s | ((unsigned)(t & 255) << 24);
            bk[r] = b;
            atomicAdd(&hist[b], 1);
        }
    }
    __syncthreads();
    sc[tid] = hist[tid]; sc[tid + 256] = hist[tid + 256];
    __syncthreads();
    for (int off = 1; off < 512; off <<= 1) {
        int i0 = tid, i1 = tid + 256;
        int v0 = (i0 >= off) ? sc[i0 - off] : 0;
        int v1 = (i1 >= off) ? sc[i1 - off] : 0;
        __syncthreads();
        sc[i0] += v0; sc[i1] += v1;
        __syncthreads();
    }
    {
        int b0 = tid, b1 = tid + 256;
        int o0 = sc[b0] - hist[b0];
        int o1 = sc[b1] - hist[b1];
        place[b0] = o0; place[b1] = o1;
        sc[b0] = o0; sc[b1] = o1;
        if (b0 < NBKT && hist[b0]) gbase[b0] = atomicAdd(&gcur[b0], hist[b0]);
        if (b1 < NBKT && hist[b1]) gbase[b1] = atomicAdd(&gcur[b1], hist[b1]);
    }
    __syncthreads();
    #pragma unroll
    for (int r = 0; r < 16; ++r) {
        if (bk[r] >= 0) {
            int p = atomicAdd(&place[bk[r]], 1);
            staging[p] = pay[r];
            bid[p] = (unsigned short)bk[r];
        }
    }
    __syncthreads();
    for (int i = tid; i < n; i += 256) {
        int b = bid[i];
        int gp = gbase[b] + (i - sc[b]);
        if (gp < CAP) slab[(size_t)b * CAP + gp] = staging[i];
    }
}

// Per bucket: histogram local dst, scan, reorder in LDS, write back in place
// (coalesced, sorted by dst). Emits rowptr/cnt/dis.
__global__ __launch_bounds__(512) void k_csr(const int* __restrict__ gcur,
                                             unsigned int* __restrict__ slab,
                                             int* __restrict__ rowptr,
                                             int* __restrict__ cnt,
                                             float* __restrict__ dis) {
    __shared__ int hist[BNODES];
    __shared__ int lofs[BNODES];
    __shared__ int place[BNODES];
    __shared__ unsigned int reord[CAP];
    int tid = threadIdx.x, b = blockIdx.x;
    if (tid < BNODES) hist[tid] = 0;
    __syncthreads();
    int count = min(gcur[b], CAP);
    unsigned int* sl = slab + (size_t)b * CAP;
    for (int i = tid; i < count; i += 512) atomicAdd(&hist[sl[i] >> 24], 1);
    __syncthreads();
    if (tid < BNODES) lofs[tid] = hist[tid];
    __syncthreads();
    for (int off = 1; off < BNODES; off <<= 1) {
        int v = 0;
        if (tid < BNODES && tid >= off) v = lofs[tid - off];
        __syncthreads();
        if (tid < BNODES) lofs[tid] += v;
        __syncthreads();
    }
    if (tid < BNODES) {
        int ex = lofs[tid] - hist[tid];
        lofs[tid] = ex;
        place[tid] = ex;
        int node = b * BNODES + tid;
        if (node < N_NODES) {
            rowptr[node] = b * CAP + ex;
            cnt[node] = hist[tid];
            dis[node] = rsqrtf((float)hist[tid] + 1.0f);
        }
    }
    __syncthreads();
    for (int i = tid; i < count; i += 512) {
        unsigned int v = sl[i];
        int dl = v >> 24;
        int p = atomicAdd(&place[dl], 1);
        reord[p] = v & 0xFFFFFFu;
    }
    __syncthreads();
    for (int i = tid; i < count; i += 512) sl[i] = reord[i];
}

// h1 = x @ W1, pre-scaled by dis[n], packed bf16. (R7-proven structure.)
// Block = 4 waves = 64 nodes. Wave w handles k-quarter [64w,64w+64) for all 64
// nodes (lane = node). W addresses are wave-uniform -> scalar-broadcast loads,
// NO LDS in the hot loop. Cross-wave reduce via small padded LDS tile.
__global__ __launch_bounds__(256) void k_linear1(const float* __restrict__ x,
                                                 const float* __restrict__ W1,
                                                 const float* __restrict__ dis,
                                                 unsigned* __restrict__ hb) {
    __shared__ float part[4][64][17];   // [wave][node][j], padded to kill conflicts
    int tid = threadIdx.x;
    int lane = tid & 63;
    int w = __builtin_amdgcn_readfirstlane(tid >> 6);
    int node0 = blockIdx.x * 64;
    int n = node0 + lane;
    float acc[HIDC];
    #pragma unroll
    for (int j = 0; j < HIDC; ++j) acc[j] = 0.f;
    if (n < N_NODES) {
        const float4* xr = (const float4*)(x + (size_t)n * F_INC + w * 64);
        const float* wq = W1 + (size_t)w * 64 * HIDC;   // wave-uniform base
        #pragma unroll
        for (int k4 = 0; k4 < 16; ++k4) {
            float4 v = xr[k4];
            const float* wk = wq + k4 * 4 * HIDC;
            #pragma unroll
            for (int j = 0; j < HIDC; ++j)
                acc[j] += v.x * wk[j] + v.y * wk[HIDC + j] + v.z * wk[2 * HIDC + j] + v.w * wk[3 * HIDC + j];
        }
    }
    #pragma unroll
    for (int j = 0; j < HIDC; ++j) part[w][lane][j] = acc[j];
    __syncthreads();
    // reduce: thread -> (node = tid>>2, j-quad = (tid&3)*4); 16 LDS reads each
    int nl = tid >> 2;
    int jq = (tid & 3) * 4;
    int nn = node0 + nl;
    if (nn >= N_NODES) return;
    float s0 = part[0][nl][jq + 0] + part[1][nl][jq + 0] + part[2][nl][jq + 0] + part[3][nl][jq + 0];
    float s1 = part[0][nl][jq + 1] + part[1][nl][jq + 1] + part[2][nl][jq + 1] + part[3][nl][jq + 1];
    float s2 = part[0][nl][jq + 2] + part[1][nl][jq + 2] + part[2][nl][jq + 2] + part[3][nl][jq + 2];
    float s3 = part[0][nl][jq + 3] + part[1][nl][jq + 3] + part[2][nl][jq + 3] + part[3][nl][jq + 3];
    float dn = dis[nn];
    uint2 o = make_uint2(pack_bf2(dn * s0, dn * s1), pack_bf2(dn * s2, dn * s3));
    *(uint2*)(hb + (size_t)nn * 8 + (tid & 3) * 2) = o;
}

// Shared gather core: lane q of node n accumulates agg pair (j = 2q, 2q+1).
__device__ __forceinline__ void gather_core(int base, int deg, int q,
                                            const unsigned* __restrict__ csr,
                                            const unsigned* __restrict__ hb,
                                            unsigned sv, float& acc0, float& acc1) {
    acc0 = bflo(sv); acc1 = bfhi(sv);
    int j = 0;
    for (; j + 3 < deg; j += 4) {
        int s0 = csr[base + j];
        int s1 = csr[base + j + 1];
        int s2 = csr[base + j + 2];
        int s3 = csr[base + j + 3];
        unsigned v0 = hb[(size_t)s0 * 8 + q];
        unsigned v1 = hb[(size_t)s1 * 8 + q];
        unsigned v2 = hb[(size_t)s2 * 8 + q];
        unsigned v3 = hb[(size_t)s3 * 8 + q];
        acc0 += (bflo(v0) + bflo(v1)) + (bflo(v2) + bflo(v3));
        acc1 += (bfhi(v0) + bfhi(v1)) + (bfhi(v2) + bfhi(v3));
    }
    for (; j < deg; ++j) {
        int s = csr[base + j];
        unsigned v = hb[(size_t)s * 8 + q];
        acc0 += bflo(v);
        acc1 += bfhi(v);
    }
}

// Layer-1 gather FUSED with bias+ELU+@W2+prescale-pack: writes next bf16 table.
__global__ __launch_bounds__(256) void k_gather_fl1(const int* __restrict__ rowptr,
                                                    const int* __restrict__ cnt,
                                                    const unsigned* __restrict__ csr,
                                                    const float* __restrict__ dis,
                                                    const unsigned* __restrict__ hb,
                                                    const float* __restrict__ b1,
                                                    const float* __restrict__ W2,
                                                    unsigned* __restrict__ hb_out) {
    __shared__ float W2s[HIDC * HIDC];
    __shared__ float b1s[HIDC];
    if (threadIdx.x < HIDC * HIDC) W2s[threadIdx.x] = W2[threadIdx.x];
    if (threadIdx.x < HIDC) b1s[threadIdx.x] = b1[threadIdx.x];
    __syncthreads();
    int idx = blockIdx.x * blockDim.x + threadIdx.x;
    int n = idx >> 3;
    if (n >= N_NODES) return;
    int q = idx & 7;
    int lane = threadIdx.x & 63;
    float acc0, acc1;
    gather_core(rowptr[n], cnt[n], q, csr, hb, hb[(size_t)n * 8 + q], acc0, acc1);
    float dn = dis[n];
    float a0 = elu1(acc0 * dn + b1s[2 * q]);
    float a1 = elu1(acc1 * dn + b1s[2 * q + 1]);
    // 8-lane shuffle matmul: h2[2q + c] = sum_k act[k] * W2[k][2q+c]
    int gb = lane & 56;
    float h0 = 0.f, h1 = 0.f;
    #pragma unroll
    for (int k2 = 0; k2 < 8; ++k2) {
        float e0 = __shfl(a0, gb + k2, 64);   // act[2*k2]
        float e1 = __shfl(a1, gb + k2, 64);   // act[2*k2+1]
        h0 += e0 * W2s[(2 * k2) * HIDC + 2 * q]     + e1 * W2s[(2 * k2 + 1) * HIDC + 2 * q];
        h1 += e0 * W2s[(2 * k2) * HIDC + 2 * q + 1] + e1 * W2s[(2 * k2 + 1) * HIDC + 2 * q + 1];
    }
    hb_out[(size_t)n * 8 + q] = pack_bf2(dn * h0, dn * h1);
}

// Layer-2 gather: z2 = elu(agg + b2), stored pre-scaled bf16 (next table).
__global__ __launch_bounds__(256) void k_gather_z(const int* __restrict__ rowptr,
                                                  const int* __restrict__ cnt,
                                                  const unsigned* __restrict__ csr,
                                                  const float* __restrict__ dis,
                                                  const unsigned* __restrict__ hb,
                                                  const float* __restrict__ bias,
                                                  unsigned* __restrict__ outp) {
    int idx = blockIdx.x * blockDim.x + threadIdx.x;
    int n = idx >> 3;
    if (n >= N_NODES) return;
    int q = idx & 7;
    float acc0, acc1;
    gather_core(rowptr[n], cnt[n], q, csr, hb, hb[(size_t)n * 8 + q], acc0, acc1);
    float dn = dis[n];
    float z0 = elu1(acc0 * dn + bias[2 * q]);
    float z1 = elu1(acc1 * dn + bias[2 * q + 1]);
    outp[(size_t)n * 8 + q] = pack_bf2(dn * z0, dn * z1);
}

// Layer-3 gather FUSED with @W3+bias+ELU+log_softmax: writes out directly.
// Lane q computes classes j in [4q, 4q+4); 8-lane-group shuffle reductions.
__global__ __launch_bounds__(256) void k_gather_fin(const int* __restrict__ rowptr,
                                                    const int* __restrict__ cnt,
                                                    const unsigned* __restrict__ csr,
                                                    const float* __restrict__ dis,
                                                    const unsigned* __restrict__ hb,
                                                    const float* __restrict__ W3,
                                                    const float* __restrict__ b3,
                                                    float* __restrict__ out) {
    __shared__ float W3s[HIDC * NCLS];
    __shared__ float b3s[NCLS];
    for (int i = threadIdx.x; i < HIDC * NCLS; i += 256) W3s[i] = W3[i];
    if (threadIdx.x < NCLS) b3s[threadIdx.x] = b3[threadIdx.x];
    __syncthreads();
    int idx = blockIdx.x * blockDim.x + threadIdx.x;
    int n = idx >> 3;
    if (n >= N_NODES) return;
    int q = idx & 7;
    int lane = threadIdx.x & 63;
    float acc0, acc1;
    gather_core(rowptr[n], cnt[n], q, csr, hb, hb[(size_t)n * 8 + q], acc0, acc1);
    float dn = dis[n];
    float g0 = acc0 * dn, g1 = acc1 * dn;      // g[2q], g[2q+1]
    int gb = lane & 56;
    int j0 = q * 4;
    float r0 = b3s[j0], r1 = b3s[j0 + 1], r2 = b3s[j0 + 2], r3 = b3s[j0 + 3];
    #pragma unroll
    for (int k2 = 0; k2 < 8; ++k2) {
        float e0 = __shfl(g0, gb + k2, 64);    // g[2*k2]
        float e1 = __shfl(g1, gb + k2, 64);    // g[2*k2+1]
        const float* wa = &W3s[(2 * k2) * NCLS + j0];
        const float* wb = &W3s[(2 * k2 + 1) * NCLS + j0];
        r0 += e0 * wa[0] + e1 * wb[0];
        r1 += e0 * wa[1] + e1 * wb[1];
        r2 += e0 * wa[2] + e1 * wb[2];
        r3 += e0 * wa[3] + e1 * wb[3];
    }
    r0 = elu1(r0); r1 = elu1(r1); r2 = elu1(r2); r3 = elu1(r3);
    float m = fmaxf(fmaxf(r0, r1), fmaxf(r2, r3));
    #pragma unroll
    for (int off = 1; off < 8; off <<= 1) m = fmaxf(m, __shfl_xor(m, off, 64));
    float s = expf(r0 - m) + expf(r1 - m) + expf(r2 - m) + expf(r3 - m);
    #pragma unroll
    for (int off = 1; off < 8; off <<= 1) s += __shfl_xor(s, off, 64);
    float lse = logf(s) + m;
    float4* o = (float4*)(out + (size_t)n * NCLS + j0);
    *o = make_float4(r0 - lse, r1 - lse, r2 - lse, r3 - lse);
}

extern "C" void kernel_launch(void* const* d_in, const int* in_sizes, int n_in,
                              void* d_out, int out_size, void* d_ws, size_t ws_size,
                              hipStream_t stream) {
    const float* x  = (const float*)d_in[0];
    const int*   ei = (const int*)d_in[1];
    const float* W1 = (const float*)d_in[2];
    const float* b1 = (const float*)d_in[3];
    const float* W2 = (const float*)d_in[4];
    const float* b2 = (const float*)d_in[5];
    const float* W3 = (const float*)d_in[6];
    const float* b3 = (const float*)d_in[7];
    float* out = (float*)d_out;
    const int* src = ei;
    const int* dst = ei + N_EDGES;

    // workspace layout (4-byte elements)
    int* wi = (int*)d_ws;
    int*          gcur   = wi;                                   // 512
    unsigned int* slab   = (unsigned int*)(wi + 512);            // NBKT*CAP = 3,603,456
    int*          rowptr = wi + 512 + NBKT * CAP;                // 102,400
    int*          cnt    = rowptr + 102400;                      // 102,400
    float*        dis    = (float*)(cnt + 102400);               // 102,400
    unsigned*     Bh     = (unsigned*)(dis + 102400);            // 819,200 (N*8 bf16-pairs)
    unsigned*     Zb     = Bh + 819200;                          // 819,200
    (void)ws_size; (void)n_in; (void)in_sizes; (void)out_size;

    auto blocks = [](long long n) { return (int)((n + 255) / 256); };
    const int GGATH = blocks((long long)N_NODES * 8);   // 3125
    const int GLIN1 = (N_NODES + 63) / 64;              // 1563 (64 nodes/block)

    k_zero_cur<<<1, 512, 0, stream>>>(gcur);
    k_bucket<<<NCHUNK, 256, 0, stream>>>(src, dst, gcur, slab);
    k_csr<<<NBKT, 512, 0, stream>>>(gcur, slab, rowptr, cnt, dis);

    // Layer 1: h1 = x@W1 (pre-scaled bf16) -> gather+bias+ELU+@W2 -> Bh'
    k_linear1<<<GLIN1, 256, 0, stream>>>(x, W1, dis, Bh);
    k_gather_fl1<<<GGATH, 256, 0, stream>>>(rowptr, cnt, slab, dis, Bh, b1, W2, Zb);
    // Layer 2: gather -> z2 = elu(agg+b2), pre-scaled bf16
    k_gather_z<<<GGATH, 256, 0, stream>>>(rowptr, cnt, slab, dis, Zb, b2, Bh);
    // Layer 3: gather -> @W3+b3 -> ELU -> log_softmax -> out
    k_gather_fin<<<GGATH, 256, 0, stream>>>(rowptr, cnt, slab, dis, Bh, W3, b3, out);
}

// Round 13
// 166.364 us; speedup vs baseline: 1.5511x; 1.1099x over previous
//
#include <hip/hip_runtime.h>
#include <math.h>

static constexpr int N_NODES = 100000;
static constexpr int N_EDGES = 3200000;
static constexpr int F_INC   = 256;
static constexpr int HIDC    = 16;
static constexpr int NCLS    = 32;

static constexpr int BNODES  = 256;                              // nodes per bucket
static constexpr int NBKT    = (N_NODES + BNODES - 1) / BNODES;  // 391
static constexpr int CAP     = 9216;                             // slab slots per bucket
static constexpr int CHUNK   = 4096;                             // edges per bucketing block
static constexpr int NCHUNK  = (N_EDGES + CHUNK - 1) / CHUNK;    // 782
static constexpr int NTILES  = N_NODES / 16;                     // 6250 (exact)

typedef __attribute__((ext_vector_type(8))) short bf16x8;
typedef __attribute__((ext_vector_type(4))) float f32x4;

// ---- bf16 pair helpers (RNE round) ----
__device__ __forceinline__ unsigned pack_bf2(float a, float b) {
    unsigned ua = __float_as_uint(a);
    unsigned ub = __float_as_uint(b);
    ua = (ua + 0x7FFFu + ((ua >> 16) & 1u)) >> 16;
    ub = (ub + 0x7FFFu + ((ub >> 16) & 1u)) & 0xFFFF0000u;
    return ua | ub;
}
__device__ __forceinline__ float bflo(unsigned v) { return __uint_as_float(v << 16); }
__device__ __forceinline__ float bfhi(unsigned v) { return __uint_as_float(v & 0xFFFF0000u); }
__device__ __forceinline__ float elu1(float t) { return t > 0.f ? t : expm1f(t); }

__global__ void k_zero_cur(int* gcur) {
    int i = threadIdx.x;
    if (i < NBKT) gcur[i] = 0;
}

// Bin a chunk of 4096 edges by dst bucket in LDS, flush bucket-sorted runs to the slab.
__global__ __launch_bounds__(256) void k_bucket(const int* __restrict__ src,
                                                const int* __restrict__ dst,
                                                int* gcur, unsigned int* __restrict__ slab) {
    __shared__ int hist[512];
    __shared__ int sc[512];
    __shared__ int place[512];
    __shared__ int gbase[512];
    __shared__ unsigned int staging[CHUNK];
    __shared__ unsigned short bid[CHUNK];
    int tid = threadIdx.x;
    int e0 = blockIdx.x * CHUNK;
    int n = min(CHUNK, N_EDGES - e0);
    hist[tid] = 0; hist[tid + 256] = 0;
    __syncthreads();
    unsigned int pay[16];
    int bk[16];
    #pragma unroll
    for (int r = 0; r < 16; ++r) {
        int i = r * 256 + tid;
        bk[r] = -1;
        if (i < n) {
            int e = e0 + i;
            int s = src[e];
            int t = dst[e];
            int b = t >> 8;
            pay[r] = (unsigned)s | ((unsigned)(t & 255) << 24);
            bk[r] = b;
            atomicAdd(&hist[b], 1);
        }
    }
    __syncthreads();
    sc[tid] = hist[tid]; sc[tid + 256] = hist[tid + 256];
    __syncthreads();
    for (int off = 1; off < 512; off <<= 1) {
        int i0 = tid, i1 = tid + 256;
        int v0 = (i0 >= off) ? sc[i0 - off] : 0;
        int v1 = (i1 >= off) ? sc[i1 - off] : 0;
        __syncthreads();
        sc[i0] += v0; sc[i1] += v1;
        __syncthreads();
    }
    {
        int b0 = tid, b1 = tid + 256;
        int o0 = sc[b0] - hist[b0];
        int o1 = sc[b1] - hist[b1];
        place[b0] = o0; place[b1] = o1;
        sc[b0] = o0; sc[b1] = o1;
        if (b0 < NBKT && hist[b0]) gbase[b0] = atomicAdd(&gcur[b0], hist[b0]);
        if (b1 < NBKT && hist[b1]) gbase[b1] = atomicAdd(&gcur[b1], hist[b1]);
    }
    __syncthreads();
    #pragma unroll
    for (int r = 0; r < 16; ++r) {
        if (bk[r] >= 0) {
            int p = atomicAdd(&place[bk[r]], 1);
            staging[p] = pay[r];
            bid[p] = (unsigned short)bk[r];
        }
    }
    __syncthreads();
    for (int i = tid; i < n; i += 256) {
        int b = bid[i];
        int gp = gbase[b] + (i - sc[b]);
        if (gp < CAP) slab[(size_t)b * CAP + gp] = staging[i];
    }
}

// Per bucket: histogram local dst, scan, reorder in LDS, write back in place
// (coalesced, sorted by dst). Emits rowptr/cnt/dis.
__global__ __launch_bounds__(512) void k_csr(const int* __restrict__ gcur,
                                             unsigned int* __restrict__ slab,
                                             int* __restrict__ rowptr,
                                             int* __restrict__ cnt,
                                             float* __restrict__ dis) {
    __shared__ int hist[BNODES];
    __shared__ int lofs[BNODES];
    __shared__ int place[BNODES];
    __shared__ unsigned int reord[CAP];
    int tid = threadIdx.x, b = blockIdx.x;
    if (tid < BNODES) hist[tid] = 0;
    __syncthreads();
    int count = min(gcur[b], CAP);
    unsigned int* sl = slab + (size_t)b * CAP;
    for (int i = tid; i < count; i += 512) atomicAdd(&hist[sl[i] >> 24], 1);
    __syncthreads();
    if (tid < BNODES) lofs[tid] = hist[tid];
    __syncthreads();
    for (int off = 1; off < BNODES; off <<= 1) {
        int v = 0;
        if (tid < BNODES && tid >= off) v = lofs[tid - off];
        __syncthreads();
        if (tid < BNODES) lofs[tid] += v;
        __syncthreads();
    }
    if (tid < BNODES) {
        int ex = lofs[tid] - hist[tid];
        lofs[tid] = ex;
        place[tid] = ex;
        int node = b * BNODES + tid;
        if (node < N_NODES) {
            rowptr[node] = b * CAP + ex;
            cnt[node] = hist[tid];
            dis[node] = rsqrtf((float)hist[tid] + 1.0f);
        }
    }
    __syncthreads();
    for (int i = tid; i < count; i += 512) {
        unsigned int v = sl[i];
        int dl = v >> 24;
        int p = atomicAdd(&place[dl], 1);
        reord[p] = v & 0xFFFFFFu;
    }
    __syncthreads();
    for (int i = tid; i < count; i += 512) sl[i] = reord[i];
}

// h1 = x @ W1 via MFMA, pre-scaled by dis[n], packed bf16.
// One WAVE per 16-node tile. Lane = (g = lane>>4, r = lane&15).
// A-frag: x[row = r][k = 32m + 8g .. +8) as bf16x8 (two float4 loads; each
// instr touches 16 rows x 64B fully-used sectors -> transaction-optimal).
// B-frag: W1[k][j] preloaded as 8 bf16x8 fragments (32 VGPRs).
// D: col = lane&15, row = (lane>>4)*4 + reg (m89-verified mapping).
__global__ __launch_bounds__(256) void k_linear1(const float* __restrict__ x,
                                                 const float* __restrict__ W1,
                                                 const float* __restrict__ dis,
                                                 unsigned* __restrict__ hb) {
    __shared__ float dtile[4][16][18];
    int tid = threadIdx.x;
    int lane = tid & 63;
    int w = tid >> 6;
    int tile = blockIdx.x * 4 + w;
    if (tile >= NTILES) return;          // no __syncthreads below; waves independent
    int g = lane >> 4;
    int r = lane & 15;
    // preload B fragments: bfr[m] elem i = bf16(W1[(32m + 8g + i)][r])
    union { uint4 u; bf16x8 v; } bfr[8];
    #pragma unroll
    for (int m = 0; m < 8; ++m) {
        unsigned uu[4];
        #pragma unroll
        for (int t = 0; t < 4; ++t) {
            int k0 = 32 * m + 8 * g + 2 * t;
            uu[t] = pack_bf2(W1[k0 * HIDC + r], W1[(k0 + 1) * HIDC + r]);
        }
        bfr[m].u = make_uint4(uu[0], uu[1], uu[2], uu[3]);
    }
    const float* xrow = x + (size_t)(tile * 16 + r) * F_INC;
    f32x4 acc = {0.f, 0.f, 0.f, 0.f};
    #pragma unroll
    for (int m = 0; m < 8; ++m) {
        int ks = 32 * m + 8 * g;
        float4 va = *(const float4*)(xrow + ks);
        float4 vb = *(const float4*)(xrow + ks + 4);
        union { uint4 u; bf16x8 v; } af;
        af.u = make_uint4(pack_bf2(va.x, va.y), pack_bf2(va.z, va.w),
                          pack_bf2(vb.x, vb.y), pack_bf2(vb.z, vb.w));
        acc = __builtin_amdgcn_mfma_f32_16x16x32_bf16(af.v, bfr[m].v, acc, 0, 0, 0);
    }
    // D -> LDS: lane holds rows 4g..4g+3 of column r
    #pragma unroll
    for (int t = 0; t < 4; ++t) dtile[w][4 * g + t][r] = acc[t];
    __builtin_amdgcn_s_waitcnt(0);       // lgkmcnt(0): LDS writes visible wave-sync
    // epilogue: lane -> (q = lane&7, rows lane>>3 and lane>>3 + 8)
    int q = lane & 7;
    #pragma unroll
    for (int h = 0; h < 2; ++h) {
        int rr = (lane >> 3) + 8 * h;
        int node = tile * 16 + rr;
        float dn = dis[node];
        hb[(size_t)node * 8 + q] =
            pack_bf2(dn * dtile[w][rr][2 * q], dn * dtile[w][rr][2 * q + 1]);
    }
}

// Shared gather core: lane q of node n accumulates agg pair (j = 2q, 2q+1).
__device__ __forceinline__ void gather_core(int base, int deg, int q,
                                            const unsigned* __restrict__ csr,
                                            const unsigned* __restrict__ hb,
                                            unsigned sv, float& acc0, float& acc1) {
    acc0 = bflo(sv); acc1 = bfhi(sv);
    int j = 0;
    for (; j + 3 < deg; j += 4) {
        int s0 = csr[base + j];
        int s1 = csr[base + j + 1];
        int s2 = csr[base + j + 2];
        int s3 = csr[base + j + 3];
        unsigned v0 = hb[(size_t)s0 * 8 + q];
        unsigned v1 = hb[(size_t)s1 * 8 + q];
        unsigned v2 = hb[(size_t)s2 * 8 + q];
        unsigned v3 = hb[(size_t)s3 * 8 + q];
        acc0 += (bflo(v0) + bflo(v1)) + (bflo(v2) + bflo(v3));
        acc1 += (bfhi(v0) + bfhi(v1)) + (bfhi(v2) + bfhi(v3));
    }
    for (; j < deg; ++j) {
        int s = csr[base + j];
        unsigned v = hb[(size_t)s * 8 + q];
        acc0 += bflo(v);
        acc1 += bfhi(v);
    }
}

// Layer-1 gather FUSED with bias+ELU+@W2+prescale-pack: writes next bf16 table.
__global__ __launch_bounds__(256) void k_gather_fl1(const int* __restrict__ rowptr,
                                                    const int* __restrict__ cnt,
                                                    const unsigned* __restrict__ csr,
                                                    const float* __restrict__ dis,
                                                    const unsigned* __restrict__ hb,
                                                    const float* __restrict__ b1,
                                                    const float* __restrict__ W2,
                                                    unsigned* __restrict__ hb_out) {
    __shared__ float W2s[HIDC * HIDC];
    __shared__ float b1s[HIDC];
    if (threadIdx.x < HIDC * HIDC) W2s[threadIdx.x] = W2[threadIdx.x];
    if (threadIdx.x < HIDC) b1s[threadIdx.x] = b1[threadIdx.x];
    __syncthreads();
    int idx = blockIdx.x * blockDim.x + threadIdx.x;
    int n = idx >> 3;
    if (n >= N_NODES) return;
    int q = idx & 7;
    int lane = threadIdx.x & 63;
    float acc0, acc1;
    gather_core(rowptr[n], cnt[n], q, csr, hb, hb[(size_t)n * 8 + q], acc0, acc1);
    float dn = dis[n];
    float a0 = elu1(acc0 * dn + b1s[2 * q]);
    float a1 = elu1(acc1 * dn + b1s[2 * q + 1]);
    // 8-lane shuffle matmul: h2[2q + c] = sum_k act[k] * W2[k][2q+c]
    int gb = lane & 56;
    float h0 = 0.f, h1 = 0.f;
    #pragma unroll
    for (int k2 = 0; k2 < 8; ++k2) {
        float e0 = __shfl(a0, gb + k2, 64);   // act[2*k2]
        float e1 = __shfl(a1, gb + k2, 64);   // act[2*k2+1]
        h0 += e0 * W2s[(2 * k2) * HIDC + 2 * q]     + e1 * W2s[(2 * k2 + 1) * HIDC + 2 * q];
        h1 += e0 * W2s[(2 * k2) * HIDC + 2 * q + 1] + e1 * W2s[(2 * k2 + 1) * HIDC + 2 * q + 1];
    }
    hb_out[(size_t)n * 8 + q] = pack_bf2(dn * h0, dn * h1);
}

// Layer-2 gather: z2 = elu(agg + b2), stored pre-scaled bf16 (next table).
__global__ __launch_bounds__(256) void k_gather_z(const int* __restrict__ rowptr,
                                                  const int* __restrict__ cnt,
                                                  const unsigned* __restrict__ csr,
                                                  const float* __restrict__ dis,
                                                  const unsigned* __restrict__ hb,
                                                  const float* __restrict__ bias,
                                                  unsigned* __restrict__ outp) {
    int idx = blockIdx.x * blockDim.x + threadIdx.x;
    int n = idx >> 3;
    if (n >= N_NODES) return;
    int q = idx & 7;
    float acc0, acc1;
    gather_core(rowptr[n], cnt[n], q, csr, hb, hb[(size_t)n * 8 + q], acc0, acc1);
    float dn = dis[n];
    float z0 = elu1(acc0 * dn + bias[2 * q]);
    float z1 = elu1(acc1 * dn + bias[2 * q + 1]);
    outp[(size_t)n * 8 + q] = pack_bf2(dn * z0, dn * z1);
}

// Layer-3 gather FUSED with @W3+bias+ELU+log_softmax: writes out directly.
// Lane q computes classes j in [4q, 4q+4); 8-lane-group shuffle reductions.
__global__ __launch_bounds__(256) void k_gather_fin(const int* __restrict__ rowptr,
                                                    const int* __restrict__ cnt,
                                                    const unsigned* __restrict__ csr,
                                                    const float* __restrict__ dis,
                                                    const unsigned* __restrict__ hb,
                                                    const float* __restrict__ W3,
                                                    const float* __restrict__ b3,
                                                    float* __restrict__ out) {
    __shared__ float W3s[HIDC * NCLS];
    __shared__ float b3s[NCLS];
    for (int i = threadIdx.x; i < HIDC * NCLS; i += 256) W3s[i] = W3[i];
    if (threadIdx.x < NCLS) b3s[threadIdx.x] = b3[threadIdx.x];
    __syncthreads();
    int idx = blockIdx.x * blockDim.x + threadIdx.x;
    int n = idx >> 3;
    if (n >= N_NODES) return;
    int q = idx & 7;
    int lane = threadIdx.x & 63;
    float acc0, acc1;
    gather_core(rowptr[n], cnt[n], q, csr, hb, hb[(size_t)n * 8 + q], acc0, acc1);
    float dn = dis[n];
    float g0 = acc0 * dn, g1 = acc1 * dn;      // g[2q], g[2q+1]
    int gb = lane & 56;
    int j0 = q * 4;
    float r0 = b3s[j0], r1 = b3s[j0 + 1], r2 = b3s[j0 + 2], r3 = b3s[j0 + 3];
    #pragma unroll
    for (int k2 = 0; k2 < 8; ++k2) {
        float e0 = __shfl(g0, gb + k2, 64);    // g[2*k2]
        float e1 = __shfl(g1, gb + k2, 64);    // g[2*k2+1]
        const float* wa = &W3s[(2 * k2) * NCLS + j0];
        const float* wb = &W3s[(2 * k2 + 1) * NCLS + j0];
        r0 += e0 * wa[0] + e1 * wb[0];
        r1 += e0 * wa[1] + e1 * wb[1];
        r2 += e0 * wa[2] + e1 * wb[2];
        r3 += e0 * wa[3] + e1 * wb[3];
    }
    r0 = elu1(r0); r1 = elu1(r1); r2 = elu1(r2); r3 = elu1(r3);
    float m = fmaxf(fmaxf(r0, r1), fmaxf(r2, r3));
    #pragma unroll
    for (int off = 1; off < 8; off <<= 1) m = fmaxf(m, __shfl_xor(m, off, 64));
    float s = expf(r0 - m) + expf(r1 - m) + expf(r2 - m) + expf(r3 - m);
    #pragma unroll
    for (int off = 1; off < 8; off <<= 1) s += __shfl_xor(s, off, 64);
    float lse = logf(s) + m;
    float4* o = (float4*)(out + (size_t)n * NCLS + j0);
    *o = make_float4(r0 - lse, r1 - lse, r2 - lse, r3 - lse);
}

extern "C" void kernel_launch(void* const* d_in, const int* in_sizes, int n_in,
                              void* d_out, int out_size, void* d_ws, size_t ws_size,
                              hipStream_t stream) {
    const float* x  = (const float*)d_in[0];
    const int*   ei = (const int*)d_in[1];
    const float* W1 = (const float*)d_in[2];
    const float* b1 = (const float*)d_in[3];
    const float* W2 = (const float*)d_in[4];
    const float* b2 = (const float*)d_in[5];
    const float* W3 = (const float*)d_in[6];
    const float* b3 = (const float*)d_in[7];
    float* out = (float*)d_out;
    const int* src = ei;
    const int* dst = ei + N_EDGES;

    // workspace layout (4-byte elements)
    int* wi = (int*)d_ws;
    int*          gcur   = wi;                                   // 512
    unsigned int* slab   = (unsigned int*)(wi + 512);            // NBKT*CAP = 3,603,456
    int*          rowptr = wi + 512 + NBKT * CAP;                // 102,400
    int*          cnt    = rowptr + 102400;                      // 102,400
    float*        dis    = (float*)(cnt + 102400);               // 102,400
    unsigned*     Bh     = (unsigned*)(dis + 102400);            // 819,200 (N*8 bf16-pairs)
    unsigned*     Zb     = Bh + 819200;                          // 819,200
    (void)ws_size; (void)n_in; (void)in_sizes; (void)out_size;

    auto blocks = [](long long n) { return (int)((n + 255) / 256); };
    const int GGATH = blocks((long long)N_NODES * 8);   // 3125
    const int GLIN1 = (NTILES + 3) / 4;                 // 1563 (4 tiles/block)

    k_zero_cur<<<1, 512, 0, stream>>>(gcur);
    k_bucket<<<NCHUNK, 256, 0, stream>>>(src, dst, gcur, slab);
    k_csr<<<NBKT, 512, 0, stream>>>(gcur, slab, rowptr, cnt, dis);

    // Layer 1: h1 = x@W1 via MFMA (pre-scaled bf16) -> gather+bias+ELU+@W2
    k_linear1<<<GLIN1, 256, 0, stream>>>(x, W1, dis, Bh);
    k_gather_fl1<<<GGATH, 256, 0, stream>>>(rowptr, cnt, slab, dis, Bh, b1, W2, Zb);
    // Layer 2: gather -> z2 = elu(agg+b2), pre-scaled bf16
    k_gather_z<<<GGATH, 256, 0, stream>>>(rowptr, cnt, slab, dis, Zb, b2, Bh);
    // Layer 3: gather -> @W3+b3 -> ELU -> log_softmax -> out
    k_gather_fin<<<GGATH, 256, 0, stream>>>(rowptr, cnt, slab, dis, Bh, W3, b3, out);
}